// Round 2
// baseline (208.111 us; speedup 1.0000x reference)
//
#include <hip/hip_runtime.h>
#include <hip/hip_bf16.h>

// Problem constants (from reference): B=2, C=3, H=W=64, N=4096.
namespace {
constexpr int BB = 2;
constexpr int NN = 4096;

// Workspace layout (in floats). Total 163840 floats = 640 KB.
constexpr int OFF_SRC4 = 0;            // float4[B*N]  (sx,sy,sz,0)
constexpr int OFF_TAR4 = 4 * BB * NN;  // float4[B*N]  (tx,ty,tz,0)
constexpr int OFF_U4   = 8 * BB * NN;  // float4[B*N]  (ux,uy,uz,|u|^2)
constexpr int OFF_W4   = 12 * BB * NN; // float4[B*N]  (wx,wy,wz,0) normalized diff
constexpr int OFF_ROW  = 16 * BB * NN; // float2[B*N]  (row max m_i, 1/den_i)
constexpr int OFF_COL  = 18 * BB * NN; // float2[B*N]  (col max M_j, 1/S_j)
}

// ---------------------------------------------------------------------------
// Setup: per-batch M = K R K^-1, o = K t; per-pixel fp32 arrays.
// ---------------------------------------------------------------------------
__global__ __launch_bounds__(256) void k_setup(
    const float* __restrict__ fsrc, const float* __restrict__ ftar,
    const float* __restrict__ Kb, const float* __restrict__ Rb,
    const float* __restrict__ tb, float* __restrict__ ws) {
  int gid = blockIdx.x * blockDim.x + threadIdx.x;
  if (gid >= BB * NN) return;
  int b = gid >> 12;
  int n = gid & (NN - 1);

  float K[9], R[9], t3[3];
#pragma unroll
  for (int k = 0; k < 9; k++) { K[k] = Kb[b * 9 + k]; R[k] = Rb[b * 9 + k]; }
#pragma unroll
  for (int k = 0; k < 3; k++) t3[k] = tb[b * 3 + k];

  // K^-1 via adjugate
  float c00 = K[4] * K[8] - K[5] * K[7];
  float c01 = K[5] * K[6] - K[3] * K[8];
  float c02 = K[3] * K[7] - K[4] * K[6];
  float det = K[0] * c00 + K[1] * c01 + K[2] * c02;
  float id = 1.0f / det;
  float Ki[9];
  Ki[0] = c00 * id; Ki[1] = (K[2] * K[7] - K[1] * K[8]) * id; Ki[2] = (K[1] * K[5] - K[2] * K[4]) * id;
  Ki[3] = c01 * id; Ki[4] = (K[0] * K[8] - K[2] * K[6]) * id; Ki[5] = (K[2] * K[3] - K[0] * K[5]) * id;
  Ki[6] = c02 * id; Ki[7] = (K[1] * K[6] - K[0] * K[7]) * id; Ki[8] = (K[0] * K[4] - K[1] * K[3]) * id;

  // M = K * (R * Ki)
  float RK[9];
#pragma unroll
  for (int i = 0; i < 3; i++)
#pragma unroll
    for (int j = 0; j < 3; j++)
      RK[i * 3 + j] = R[i * 3 + 0] * Ki[j] + R[i * 3 + 1] * Ki[3 + j] + R[i * 3 + 2] * Ki[6 + j];
  float M3[9];
#pragma unroll
  for (int i = 0; i < 3; i++)
#pragma unroll
    for (int j = 0; j < 3; j++)
      M3[i * 3 + j] = K[i * 3 + 0] * RK[j] + K[i * 3 + 1] * RK[3 + j] + K[i * 3 + 2] * RK[6 + j];
  float o0 = K[0] * t3[0] + K[1] * t3[1] + K[2] * t3[2];
  float o1 = K[3] * t3[0] + K[4] * t3[1] + K[5] * t3[2];
  float o2 = K[6] * t3[0] + K[7] * t3[1] + K[8] * t3[2];

  // features: layout (B,C,H,W) flat -> b*3*N + c*N + n
  float sx = fsrc[b * 3 * NN + 0 * NN + n];
  float sy = fsrc[b * 3 * NN + 1 * NN + n];
  float sz = fsrc[b * 3 * NN + 2 * NN + n];
  float tx = ftar[b * 3 * NN + 0 * NN + n];
  float ty = ftar[b * 3 * NN + 1 * NN + n];
  float tz = ftar[b * 3 * NN + 2 * NN + n];

  float ux = sx - o0, uy = sy - o1, uz = sz - o2;
  float usq = ux * ux + uy * uy + uz * uz;

  // pix = (h, w, 1), n = h*64 + w
  float px = (float)(n >> 6), py = (float)(n & 63);
  float vx = M3[0] * px + M3[1] * py + M3[2];
  float vy = M3[3] * px + M3[4] * py + M3[5];
  float vz = M3[6] * px + M3[7] * py + M3[8];
  float invn = rsqrtf(vx * vx + vy * vy + vz * vz);

  float4* src4 = (float4*)(ws + OFF_SRC4);
  float4* tar4 = (float4*)(ws + OFF_TAR4);
  float4* u4 = (float4*)(ws + OFF_U4);
  float4* w4 = (float4*)(ws + OFF_W4);
  src4[gid] = make_float4(sx, sy, sz, 0.f);
  tar4[gid] = make_float4(tx, ty, tz, 0.f);
  u4[gid] = make_float4(ux, uy, uz, usq);
  w4[gid] = make_float4(vx * invn, vy * invn, vz * invn, 0.f);
}

// ---------------------------------------------------------------------------
// Pass 1: row stats of the epipolar-softmax logits t = 50*d  (softmax over j).
// One wave handles 4 rows; lanes stride j.
// ---------------------------------------------------------------------------
__global__ __launch_bounds__(256) void k_pass1(float* __restrict__ ws) {
  const float4* u4 = (const float4*)(ws + OFF_U4);
  const float4* w4 = (const float4*)(ws + OFF_W4);
  float2* rowst = (float2*)(ws + OFF_ROW);
  int wid = (blockIdx.x * 256 + threadIdx.x) >> 6;
  int lane = threadIdx.x & 63;
  int g0 = wid * 4;
  int b = g0 >> 12;

  float ux[4], uy[4], uz[4], us[4];
#pragma unroll
  for (int r = 0; r < 4; r++) {
    float4 u = u4[g0 + r];
    ux[r] = u.x; uy[r] = u.y; uz[r] = u.z; us[r] = u.w;
  }
  float m[4] = {-1e30f, -1e30f, -1e30f, -1e30f};
  float s[4] = {0.f, 0.f, 0.f, 0.f};
  const float4* wb = w4 + b * NN;
  for (int j = lane; j < NN; j += 64) {
    float4 w = wb[j];
#pragma unroll
    for (int r = 0; r < 4; r++) {
      float dot = ux[r] * w.x + uy[r] * w.y + uz[r] * w.z;
      float d2 = fmaxf(us[r] - dot * dot, 0.f);
      float t = 50.f * sqrtf(d2);
      float nm = fmaxf(m[r], t);
      s[r] = s[r] * __expf(m[r] - nm) + __expf(t - nm);
      m[r] = nm;
    }
  }
#pragma unroll
  for (int off = 32; off; off >>= 1) {
#pragma unroll
    for (int r = 0; r < 4; r++) {
      float mo = __shfl_xor(m[r], off);
      float so = __shfl_xor(s[r], off);
      float nm = fmaxf(m[r], mo);
      s[r] = s[r] * __expf(m[r] - nm) + so * __expf(mo - nm);
      m[r] = nm;
    }
  }
  if (lane == 0) {
#pragma unroll
    for (int r = 0; r < 4; r++) rowst[g0 + r] = make_float2(m[r], 1.f / s[r]);
  }
}

// ---------------------------------------------------------------------------
// Pass 2: column stats of Aw (softmax over i). One wave handles 4 columns.
// ---------------------------------------------------------------------------
__global__ __launch_bounds__(256) void k_pass2(float* __restrict__ ws) {
  const float4* u4 = (const float4*)(ws + OFF_U4);
  const float4* w4 = (const float4*)(ws + OFF_W4);
  const float4* src4 = (const float4*)(ws + OFF_SRC4);
  const float4* tar4 = (const float4*)(ws + OFF_TAR4);
  const float2* rowst = (const float2*)(ws + OFF_ROW);
  float2* colst = (float2*)(ws + OFF_COL);
  int wid = (blockIdx.x * 256 + threadIdx.x) >> 6;
  int lane = threadIdx.x & 63;
  int c0 = wid * 4;
  int b = c0 >> 12;

  float wx[4], wy[4], wz[4], tx[4], ty[4], tz[4];
#pragma unroll
  for (int r = 0; r < 4; r++) {
    float4 w = w4[c0 + r];
    float4 tt = tar4[c0 + r];
    wx[r] = w.x; wy[r] = w.y; wz[r] = w.z;
    tx[r] = tt.x; ty[r] = tt.y; tz[r] = tt.z;
  }
  float M[4] = {-1e30f, -1e30f, -1e30f, -1e30f};
  float S[4] = {0.f, 0.f, 0.f, 0.f};
  int base = b * NN;
  for (int i = lane; i < NN; i += 64) {
    float4 u = u4[base + i];
    float4 sv = src4[base + i];
    float2 rs = rowst[base + i];
#pragma unroll
    for (int r = 0; r < 4; r++) {
      float dot = u.x * wx[r] + u.y * wy[r] + u.z * wz[r];
      float d2 = fmaxf(u.w - dot * dot, 0.f);
      float t = 50.f * sqrtf(d2);
      float e = __expf(t - rs.x);
      float wgt = 1.f - e * rs.y;
      float A = sv.x * tx[r] + sv.y * ty[r] + sv.z * tz[r];
      float Aw = A * wgt;
      float nm = fmaxf(M[r], Aw);
      S[r] = S[r] * __expf(M[r] - nm) + __expf(Aw - nm);
      M[r] = nm;
    }
  }
#pragma unroll
  for (int off = 32; off; off >>= 1) {
#pragma unroll
    for (int r = 0; r < 4; r++) {
      float mo = __shfl_xor(M[r], off);
      float so = __shfl_xor(S[r], off);
      float nm = fmaxf(M[r], mo);
      S[r] = S[r] * __expf(M[r] - nm) + so * __expf(mo - nm);
      M[r] = nm;
    }
  }
  if (lane == 0) {
#pragma unroll
    for (int r = 0; r < 4; r++) colst[c0 + r] = make_float2(M[r], 1.f / S[r]);
  }
}

// ---------------------------------------------------------------------------
// Pass 3: out[b,i,c] = sum_j exp(Aw_ij - M_j)/S_j * src[c,j]. Wave per 4 rows.
// ---------------------------------------------------------------------------
__global__ __launch_bounds__(256) void k_pass3(const float* __restrict__ ws,
                                               float* __restrict__ out) {
  const float4* u4 = (const float4*)(ws + OFF_U4);
  const float4* w4 = (const float4*)(ws + OFF_W4);
  const float4* src4 = (const float4*)(ws + OFF_SRC4);
  const float4* tar4 = (const float4*)(ws + OFF_TAR4);
  const float2* rowst = (const float2*)(ws + OFF_ROW);
  const float2* colst = (const float2*)(ws + OFF_COL);
  int wid = (blockIdx.x * 256 + threadIdx.x) >> 6;
  int lane = threadIdx.x & 63;
  int g0 = wid * 4;
  int b = g0 >> 12;

  float ux[4], uy[4], uz[4], us[4], mrow[4], invden[4], sx[4], sy[4], sz[4];
#pragma unroll
  for (int r = 0; r < 4; r++) {
    float4 u = u4[g0 + r];
    float2 rs = rowst[g0 + r];
    float4 sv = src4[g0 + r];
    ux[r] = u.x; uy[r] = u.y; uz[r] = u.z; us[r] = u.w;
    mrow[r] = rs.x; invden[r] = rs.y;
    sx[r] = sv.x; sy[r] = sv.y; sz[r] = sv.z;
  }
  float acc[4][3];
#pragma unroll
  for (int r = 0; r < 4; r++) { acc[r][0] = 0.f; acc[r][1] = 0.f; acc[r][2] = 0.f; }

  int base = b * NN;
  for (int j = lane; j < NN; j += 64) {
    float4 w = w4[base + j];
    float4 tt = tar4[base + j];
    float4 sj = src4[base + j];
    float2 cs = colst[base + j];
#pragma unroll
    for (int r = 0; r < 4; r++) {
      float dot = ux[r] * w.x + uy[r] * w.y + uz[r] * w.z;
      float d2 = fmaxf(us[r] - dot * dot, 0.f);
      float t = 50.f * sqrtf(d2);
      float e = __expf(t - mrow[r]);
      float wgt = 1.f - e * invden[r];
      float A = sx[r] * tt.x + sy[r] * tt.y + sz[r] * tt.z;
      float Aw = A * wgt;
      float p = __expf(Aw - cs.x) * cs.y;
      acc[r][0] += p * sj.x;
      acc[r][1] += p * sj.y;
      acc[r][2] += p * sj.z;
    }
  }
#pragma unroll
  for (int off = 32; off; off >>= 1) {
#pragma unroll
    for (int r = 0; r < 4; r++) {
      acc[r][0] += __shfl_xor(acc[r][0], off);
      acc[r][1] += __shfl_xor(acc[r][1], off);
      acc[r][2] += __shfl_xor(acc[r][2], off);
    }
  }
  if (lane == 0) {
#pragma unroll
    for (int r = 0; r < 4; r++) {
      int g = g0 + r;
      out[g * 3 + 0] = acc[r][0];
      out[g * 3 + 1] = acc[r][1];
      out[g * 3 + 2] = acc[r][2];
    }
  }
}

extern "C" void kernel_launch(void* const* d_in, const int* in_sizes, int n_in,
                              void* d_out, int out_size, void* d_ws, size_t ws_size,
                              hipStream_t stream) {
  (void)in_sizes; (void)n_in; (void)out_size; (void)ws_size;
  const float* ftar = (const float*)d_in[0];
  const float* fsrc = (const float*)d_in[1];
  const float* K = (const float*)d_in[2];
  const float* R = (const float*)d_in[3];
  const float* t = (const float*)d_in[4];
  float* ws = (float*)d_ws;
  float* out = (float*)d_out;

  k_setup<<<dim3((BB * NN + 255) / 256), dim3(256), 0, stream>>>(fsrc, ftar, K, R, t, ws);
  // 8192 rows(/cols) / 4 per wave = 2048 waves = 512 blocks of 4 waves
  k_pass1<<<dim3(512), dim3(256), 0, stream>>>(ws);
  k_pass2<<<dim3(512), dim3(256), 0, stream>>>(ws);
  k_pass3<<<dim3(512), dim3(256), 0, stream>>>(ws, out);
}

// Round 3
// 169.807 us; speedup vs baseline: 1.2256x; 1.2256x over previous
//
#include <hip/hip_runtime.h>
#include <hip/hip_bf16.h>

// Problem constants (from reference): B=2, C=3, H=W=64, N=4096.
namespace {
constexpr int BB = 2;
constexpr int NN = 4096;

// Workspace layout (in floats). Total 640 KB — fully L2-resident.
constexpr int OFF_SRC4 = 0;            // float4[B*N]  (sx,sy,sz,0)
constexpr int OFF_TAR4 = 4 * BB * NN;  // float4[B*N]  (tx,ty,tz,0)
constexpr int OFF_U4   = 8 * BB * NN;  // float4[B*N]  (ux,uy,uz,|u|^2)
constexpr int OFF_W4   = 12 * BB * NN; // float4[B*N]  (wx,wy,wz,0) normalized diff
constexpr int OFF_ROW  = 16 * BB * NN; // float2[B*N]  (row max m_i, 1/den_i)
constexpr int OFF_COL  = 18 * BB * NN; // float2[B*N]  (col sub-const Mb_j, 1/S_j)
}

// ---------------------------------------------------------------------------
// Setup: per-batch M = K R K^-1, o = K t; per-pixel fp32 arrays.
// ---------------------------------------------------------------------------
__global__ __launch_bounds__(256) void k_setup(
    const float* __restrict__ fsrc, const float* __restrict__ ftar,
    const float* __restrict__ Kb, const float* __restrict__ Rb,
    const float* __restrict__ tb, float* __restrict__ ws) {
  int gid = blockIdx.x * blockDim.x + threadIdx.x;
  if (gid >= BB * NN) return;
  int b = gid >> 12;
  int n = gid & (NN - 1);

  float K[9], R[9], t3[3];
#pragma unroll
  for (int k = 0; k < 9; k++) { K[k] = Kb[b * 9 + k]; R[k] = Rb[b * 9 + k]; }
#pragma unroll
  for (int k = 0; k < 3; k++) t3[k] = tb[b * 3 + k];

  // K^-1 via adjugate
  float c00 = K[4] * K[8] - K[5] * K[7];
  float c01 = K[5] * K[6] - K[3] * K[8];
  float c02 = K[3] * K[7] - K[4] * K[6];
  float det = K[0] * c00 + K[1] * c01 + K[2] * c02;
  float id = 1.0f / det;
  float Ki[9];
  Ki[0] = c00 * id; Ki[1] = (K[2] * K[7] - K[1] * K[8]) * id; Ki[2] = (K[1] * K[5] - K[2] * K[4]) * id;
  Ki[3] = c01 * id; Ki[4] = (K[0] * K[8] - K[2] * K[6]) * id; Ki[5] = (K[2] * K[3] - K[0] * K[5]) * id;
  Ki[6] = c02 * id; Ki[7] = (K[1] * K[6] - K[0] * K[7]) * id; Ki[8] = (K[0] * K[4] - K[1] * K[3]) * id;

  float RK[9];
#pragma unroll
  for (int i = 0; i < 3; i++)
#pragma unroll
    for (int j = 0; j < 3; j++)
      RK[i * 3 + j] = R[i * 3 + 0] * Ki[j] + R[i * 3 + 1] * Ki[3 + j] + R[i * 3 + 2] * Ki[6 + j];
  float M3[9];
#pragma unroll
  for (int i = 0; i < 3; i++)
#pragma unroll
    for (int j = 0; j < 3; j++)
      M3[i * 3 + j] = K[i * 3 + 0] * RK[j] + K[i * 3 + 1] * RK[3 + j] + K[i * 3 + 2] * RK[6 + j];
  float o0 = K[0] * t3[0] + K[1] * t3[1] + K[2] * t3[2];
  float o1 = K[3] * t3[0] + K[4] * t3[1] + K[5] * t3[2];
  float o2 = K[6] * t3[0] + K[7] * t3[1] + K[8] * t3[2];

  float sx = fsrc[b * 3 * NN + 0 * NN + n];
  float sy = fsrc[b * 3 * NN + 1 * NN + n];
  float sz = fsrc[b * 3 * NN + 2 * NN + n];
  float tx = ftar[b * 3 * NN + 0 * NN + n];
  float ty = ftar[b * 3 * NN + 1 * NN + n];
  float tz = ftar[b * 3 * NN + 2 * NN + n];

  float ux = sx - o0, uy = sy - o1, uz = sz - o2;
  float usq = ux * ux + uy * uy + uz * uz;

  float px = (float)(n >> 6), py = (float)(n & 63);
  float vx = M3[0] * px + M3[1] * py + M3[2];
  float vy = M3[3] * px + M3[4] * py + M3[5];
  float vz = M3[6] * px + M3[7] * py + M3[8];
  float invn = rsqrtf(vx * vx + vy * vy + vz * vz);

  float4* src4 = (float4*)(ws + OFF_SRC4);
  float4* tar4 = (float4*)(ws + OFF_TAR4);
  float4* u4 = (float4*)(ws + OFF_U4);
  float4* w4 = (float4*)(ws + OFF_W4);
  src4[gid] = make_float4(sx, sy, sz, 0.f);
  tar4[gid] = make_float4(tx, ty, tz, 0.f);
  u4[gid] = make_float4(ux, uy, uz, usq);
  w4[gid] = make_float4(vx * invn, vy * invn, vz * invn, 0.f);
}

// ---------------------------------------------------------------------------
// Pass 1: row softmax stats over j. Block = 4 waves cooperating on 4 rows,
// j split 4 ways. Two-loop: cheap max(d2) pre-loop (no trans), then exp-sum.
// ---------------------------------------------------------------------------
__global__ __launch_bounds__(256, 6) void k_pass1(float* __restrict__ ws) {
  __shared__ float sred[4][4];
  const float4* u4 = (const float4*)(ws + OFF_U4);
  const float4* w4 = (const float4*)(ws + OFF_W4);
  float2* rowst = (float2*)(ws + OFF_ROW);
  int tid = threadIdx.x, wid = tid >> 6, lane = tid & 63;
  int g0 = blockIdx.x * 4;
  int b = g0 >> 12;

  float ux[4], uy[4], uz[4], us[4];
#pragma unroll
  for (int r = 0; r < 4; r++) {
    float4 u = u4[g0 + r];
    ux[r] = u.x; uy[r] = u.y; uz[r] = u.z; us[r] = u.w;
  }
  const float4* wb = w4 + b * NN;

  // Loop A: max of d2 (no transcendentals)
  float mx[4] = {0.f, 0.f, 0.f, 0.f};
  for (int j = wid * 64 + lane; j < NN; j += 256) {
    float4 w = wb[j];
#pragma unroll
    for (int r = 0; r < 4; r++) {
      float dot = ux[r] * w.x + uy[r] * w.y + uz[r] * w.z;
      float d2 = us[r] - dot * dot;
      mx[r] = fmaxf(mx[r], d2);
    }
  }
#pragma unroll
  for (int off = 32; off; off >>= 1)
#pragma unroll
    for (int r = 0; r < 4; r++) mx[r] = fmaxf(mx[r], __shfl_xor(mx[r], off));
  if (lane == 0) {
#pragma unroll
    for (int r = 0; r < 4; r++) sred[wid][r] = mx[r];
  }
  __syncthreads();
  float m[4];
#pragma unroll
  for (int r = 0; r < 4; r++)
    m[r] = 50.f * sqrtf(fmaxf(fmaxf(sred[0][r], sred[1][r]), fmaxf(sred[2][r], sred[3][r])));
  __syncthreads();

  // Loop B: sum of exp(t - m)
  float s[4] = {0.f, 0.f, 0.f, 0.f};
  for (int j = wid * 64 + lane; j < NN; j += 256) {
    float4 w = wb[j];
#pragma unroll
    for (int r = 0; r < 4; r++) {
      float dot = ux[r] * w.x + uy[r] * w.y + uz[r] * w.z;
      float d2 = fmaxf(us[r] - dot * dot, 0.f);
      float t = 50.f * sqrtf(d2);
      s[r] += __expf(t - m[r]);
    }
  }
#pragma unroll
  for (int off = 32; off; off >>= 1)
#pragma unroll
    for (int r = 0; r < 4; r++) s[r] += __shfl_xor(s[r], off);
  if (lane == 0) {
#pragma unroll
    for (int r = 0; r < 4; r++) sred[wid][r] = s[r];
  }
  __syncthreads();
  if (tid == 0) {
#pragma unroll
    for (int r = 0; r < 4; r++) {
      float tot = sred[0][r] + sred[1][r] + sred[2][r] + sred[3][r];
      rowst[g0 + r] = make_float2(m[r], 1.f / tot);
    }
  }
}

// ---------------------------------------------------------------------------
// Pass 2: column softmax stats over i. Subtract the BOUND Mb_j = max_i |A_ij|
// (weight in [0,1] => Aw <= |A| <= Mb; S >= exp(-2*Mb) stays normal fp32).
// Softmax ratio is exact for any subtracted constant.
// ---------------------------------------------------------------------------
__global__ __launch_bounds__(256, 6) void k_pass2(float* __restrict__ ws) {
  __shared__ float sred[4][4];
  const float4* u4 = (const float4*)(ws + OFF_U4);
  const float4* w4 = (const float4*)(ws + OFF_W4);
  const float4* src4 = (const float4*)(ws + OFF_SRC4);
  const float4* tar4 = (const float4*)(ws + OFF_TAR4);
  const float2* rowst = (const float2*)(ws + OFF_ROW);
  float2* colst = (float2*)(ws + OFF_COL);
  int tid = threadIdx.x, wid = tid >> 6, lane = tid & 63;
  int c0 = blockIdx.x * 4;
  int b = c0 >> 12;
  int base = b * NN;

  float wx[4], wy[4], wz[4], tx[4], ty[4], tz[4];
#pragma unroll
  for (int r = 0; r < 4; r++) {
    float4 w = w4[c0 + r];
    float4 tt = tar4[c0 + r];
    wx[r] = w.x; wy[r] = w.y; wz[r] = w.z;
    tx[r] = tt.x; ty[r] = tt.y; tz[r] = tt.z;
  }

  // Loop A: Mb = max |A| (no transcendentals)
  float mb[4] = {0.f, 0.f, 0.f, 0.f};
  for (int i = wid * 64 + lane; i < NN; i += 256) {
    float4 sv = src4[base + i];
#pragma unroll
    for (int r = 0; r < 4; r++) {
      float A = sv.x * tx[r] + sv.y * ty[r] + sv.z * tz[r];
      mb[r] = fmaxf(mb[r], fabsf(A));
    }
  }
#pragma unroll
  for (int off = 32; off; off >>= 1)
#pragma unroll
    for (int r = 0; r < 4; r++) mb[r] = fmaxf(mb[r], __shfl_xor(mb[r], off));
  if (lane == 0) {
#pragma unroll
    for (int r = 0; r < 4; r++) sred[wid][r] = mb[r];
  }
  __syncthreads();
  float Mb[4];
#pragma unroll
  for (int r = 0; r < 4; r++)
    Mb[r] = fmaxf(fmaxf(sred[0][r], sred[1][r]), fmaxf(sred[2][r], sred[3][r]));
  __syncthreads();

  // Loop B: S = sum exp(Aw - Mb)
  float S[4] = {0.f, 0.f, 0.f, 0.f};
  for (int i = wid * 64 + lane; i < NN; i += 256) {
    float4 u = u4[base + i];
    float4 sv = src4[base + i];
    float2 rs = rowst[base + i];
#pragma unroll
    for (int r = 0; r < 4; r++) {
      float dot = u.x * wx[r] + u.y * wy[r] + u.z * wz[r];
      float d2 = fmaxf(u.w - dot * dot, 0.f);
      float t = 50.f * sqrtf(d2);
      float e = __expf(t - rs.x);
      float wgt = 1.f - e * rs.y;
      float A = sv.x * tx[r] + sv.y * ty[r] + sv.z * tz[r];
      float Aw = A * wgt;
      S[r] += __expf(Aw - Mb[r]);
    }
  }
#pragma unroll
  for (int off = 32; off; off >>= 1)
#pragma unroll
    for (int r = 0; r < 4; r++) S[r] += __shfl_xor(S[r], off);
  if (lane == 0) {
#pragma unroll
    for (int r = 0; r < 4; r++) sred[wid][r] = S[r];
  }
  __syncthreads();
  if (tid == 0) {
#pragma unroll
    for (int r = 0; r < 4; r++) {
      float tot = sred[0][r] + sred[1][r] + sred[2][r] + sred[3][r];
      colst[c0 + r] = make_float2(Mb[r], 1.f / tot);
    }
  }
}

// ---------------------------------------------------------------------------
// Pass 3: out[b,i,c] = sum_j exp(Aw_ij - Mb_j)/S_j * src[c,j].
// Block = 4 waves on 4 rows, j split 4 ways, LDS merge of acc.
// ---------------------------------------------------------------------------
__global__ __launch_bounds__(256, 4) void k_pass3(const float* __restrict__ ws,
                                                  float* __restrict__ out) {
  __shared__ float sacc[4][12];
  const float4* u4 = (const float4*)(ws + OFF_U4);
  const float4* w4 = (const float4*)(ws + OFF_W4);
  const float4* src4 = (const float4*)(ws + OFF_SRC4);
  const float4* tar4 = (const float4*)(ws + OFF_TAR4);
  const float2* rowst = (const float2*)(ws + OFF_ROW);
  const float2* colst = (const float2*)(ws + OFF_COL);
  int tid = threadIdx.x, wid = tid >> 6, lane = tid & 63;
  int g0 = blockIdx.x * 4;
  int b = g0 >> 12;
  int base = b * NN;

  float ux[4], uy[4], uz[4], us[4], mrow[4], invden[4], sx[4], sy[4], sz[4];
#pragma unroll
  for (int r = 0; r < 4; r++) {
    float4 u = u4[g0 + r];
    float2 rs = rowst[g0 + r];
    float4 sv = src4[g0 + r];
    ux[r] = u.x; uy[r] = u.y; uz[r] = u.z; us[r] = u.w;
    mrow[r] = rs.x; invden[r] = rs.y;
    sx[r] = sv.x; sy[r] = sv.y; sz[r] = sv.z;
  }
  float acc[4][3];
#pragma unroll
  for (int r = 0; r < 4; r++) { acc[r][0] = 0.f; acc[r][1] = 0.f; acc[r][2] = 0.f; }

  for (int j = wid * 64 + lane; j < NN; j += 256) {
    float4 w = w4[base + j];
    float4 tt = tar4[base + j];
    float4 sj = src4[base + j];
    float2 cs = colst[base + j];
#pragma unroll
    for (int r = 0; r < 4; r++) {
      float dot = ux[r] * w.x + uy[r] * w.y + uz[r] * w.z;
      float d2 = fmaxf(us[r] - dot * dot, 0.f);
      float t = 50.f * sqrtf(d2);
      float e = __expf(t - mrow[r]);
      float wgt = 1.f - e * invden[r];
      float A = sx[r] * tt.x + sy[r] * tt.y + sz[r] * tt.z;
      float Aw = A * wgt;
      float p = __expf(Aw - cs.x) * cs.y;
      acc[r][0] += p * sj.x;
      acc[r][1] += p * sj.y;
      acc[r][2] += p * sj.z;
    }
  }
#pragma unroll
  for (int off = 32; off; off >>= 1)
#pragma unroll
    for (int r = 0; r < 4; r++) {
      acc[r][0] += __shfl_xor(acc[r][0], off);
      acc[r][1] += __shfl_xor(acc[r][1], off);
      acc[r][2] += __shfl_xor(acc[r][2], off);
    }
  if (lane == 0) {
#pragma unroll
    for (int r = 0; r < 4; r++) {
      sacc[wid][r * 3 + 0] = acc[r][0];
      sacc[wid][r * 3 + 1] = acc[r][1];
      sacc[wid][r * 3 + 2] = acc[r][2];
    }
  }
  __syncthreads();
  if (tid < 12) {
    float v = sacc[0][tid] + sacc[1][tid] + sacc[2][tid] + sacc[3][tid];
    out[g0 * 3 + tid] = v;
  }
}

extern "C" void kernel_launch(void* const* d_in, const int* in_sizes, int n_in,
                              void* d_out, int out_size, void* d_ws, size_t ws_size,
                              hipStream_t stream) {
  (void)in_sizes; (void)n_in; (void)out_size; (void)ws_size;
  const float* ftar = (const float*)d_in[0];
  const float* fsrc = (const float*)d_in[1];
  const float* K = (const float*)d_in[2];
  const float* R = (const float*)d_in[3];
  const float* t = (const float*)d_in[4];
  float* ws = (float*)d_ws;
  float* out = (float*)d_out;

  k_setup<<<dim3((BB * NN + 255) / 256), dim3(256), 0, stream>>>(fsrc, ftar, K, R, t, ws);
  // 8192 rows(/cols) / 4 per block, 4 waves cooperate per block
  k_pass1<<<dim3(2048), dim3(256), 0, stream>>>(ws);
  k_pass2<<<dim3(2048), dim3(256), 0, stream>>>(ws);
  k_pass3<<<dim3(2048), dim3(256), 0, stream>>>(ws, out);
}

// Round 4
// 134.596 us; speedup vs baseline: 1.5462x; 1.2616x over previous
//
#include <hip/hip_runtime.h>
#include <hip/hip_bf16.h>

// Problem constants (from reference): B=2, C=3, H=W=64, N=4096.
namespace {
constexpr int BB = 2;
constexpr int NN = 4096;

// Workspace layout (in floats). ~640 KB — fully L2-resident.
constexpr int OFF_SRC4 = 0;            // float4[B*N]  (sx,sy,sz,0)
constexpr int OFF_TAR4 = 4 * BB * NN;  // float4[B*N]  (tx,ty,tz,0)
constexpr int OFF_U4   = 8 * BB * NN;  // float4[B*N]  (ux,uy,uz,|u|^2)
constexpr int OFF_W4   = 12 * BB * NN; // float4[B*N]  (wx,wy,wz,0) normalized diff
constexpr int OFF_ROW  = 16 * BB * NN; // float2[B*N]  (row max m_i, 1/den_i)
constexpr int OFF_COL  = 18 * BB * NN; // float2[B*N]  (col sub-const Mb_j, 1/S_j)
constexpr int OFF_NMAX = 20 * BB * NN; // float[B]     max_i |src_i| (uint-bits atomicMax)
}

__device__ __forceinline__ float fsqrt(float x) { return __builtin_amdgcn_sqrtf(x); }

// ---------------------------------------------------------------------------
// Setup: per-batch M = K R K^-1, o = K t; per-pixel fp32 arrays; max|src| per b.
// ---------------------------------------------------------------------------
__global__ __launch_bounds__(256) void k_setup(
    const float* __restrict__ fsrc, const float* __restrict__ ftar,
    const float* __restrict__ Kb, const float* __restrict__ Rb,
    const float* __restrict__ tb, float* __restrict__ ws) {
  int gid = blockIdx.x * blockDim.x + threadIdx.x;
  if (gid >= BB * NN) return;
  int b = gid >> 12;
  int n = gid & (NN - 1);

  float K[9], R[9], t3[3];
#pragma unroll
  for (int k = 0; k < 9; k++) { K[k] = Kb[b * 9 + k]; R[k] = Rb[b * 9 + k]; }
#pragma unroll
  for (int k = 0; k < 3; k++) t3[k] = tb[b * 3 + k];

  // K^-1 via adjugate
  float c00 = K[4] * K[8] - K[5] * K[7];
  float c01 = K[5] * K[6] - K[3] * K[8];
  float c02 = K[3] * K[7] - K[4] * K[6];
  float det = K[0] * c00 + K[1] * c01 + K[2] * c02;
  float id = 1.0f / det;
  float Ki[9];
  Ki[0] = c00 * id; Ki[1] = (K[2] * K[7] - K[1] * K[8]) * id; Ki[2] = (K[1] * K[5] - K[2] * K[4]) * id;
  Ki[3] = c01 * id; Ki[4] = (K[0] * K[8] - K[2] * K[6]) * id; Ki[5] = (K[2] * K[3] - K[0] * K[5]) * id;
  Ki[6] = c02 * id; Ki[7] = (K[1] * K[6] - K[0] * K[7]) * id; Ki[8] = (K[0] * K[4] - K[1] * K[3]) * id;

  float RK[9];
#pragma unroll
  for (int i = 0; i < 3; i++)
#pragma unroll
    for (int j = 0; j < 3; j++)
      RK[i * 3 + j] = R[i * 3 + 0] * Ki[j] + R[i * 3 + 1] * Ki[3 + j] + R[i * 3 + 2] * Ki[6 + j];
  float M3[9];
#pragma unroll
  for (int i = 0; i < 3; i++)
#pragma unroll
    for (int j = 0; j < 3; j++)
      M3[i * 3 + j] = K[i * 3 + 0] * RK[j] + K[i * 3 + 1] * RK[3 + j] + K[i * 3 + 2] * RK[6 + j];
  float o0 = K[0] * t3[0] + K[1] * t3[1] + K[2] * t3[2];
  float o1 = K[3] * t3[0] + K[4] * t3[1] + K[5] * t3[2];
  float o2 = K[6] * t3[0] + K[7] * t3[1] + K[8] * t3[2];

  float sx = fsrc[b * 3 * NN + 0 * NN + n];
  float sy = fsrc[b * 3 * NN + 1 * NN + n];
  float sz = fsrc[b * 3 * NN + 2 * NN + n];
  float tx = ftar[b * 3 * NN + 0 * NN + n];
  float ty = ftar[b * 3 * NN + 1 * NN + n];
  float tz = ftar[b * 3 * NN + 2 * NN + n];

  float ux = sx - o0, uy = sy - o1, uz = sz - o2;
  float usq = ux * ux + uy * uy + uz * uz;

  float px = (float)(n >> 6), py = (float)(n & 63);
  float vx = M3[0] * px + M3[1] * py + M3[2];
  float vy = M3[3] * px + M3[4] * py + M3[5];
  float vz = M3[6] * px + M3[7] * py + M3[8];
  float invn = rsqrtf(vx * vx + vy * vy + vz * vz);

  float4* src4 = (float4*)(ws + OFF_SRC4);
  float4* tar4 = (float4*)(ws + OFF_TAR4);
  float4* u4 = (float4*)(ws + OFF_U4);
  float4* w4 = (float4*)(ws + OFF_W4);
  src4[gid] = make_float4(sx, sy, sz, 0.f);
  tar4[gid] = make_float4(tx, ty, tz, 0.f);
  u4[gid] = make_float4(ux, uy, uz, usq);
  w4[gid] = make_float4(vx * invn, vy * invn, vz * invn, 0.f);

  // per-batch max |src| (blocks are single-batch: 4096 % 256 == 0)
  float ns = fsqrt(sx * sx + sy * sy + sz * sz);
#pragma unroll
  for (int off = 32; off; off >>= 1) ns = fmaxf(ns, __shfl_xor(ns, off));
  if ((threadIdx.x & 63) == 0)
    atomicMax((unsigned int*)(ws + OFF_NMAX + b), __float_as_uint(ns));
}

// ---------------------------------------------------------------------------
// Pass 1: row softmax stats over j. Block = 4 waves on 8 rows, j split 4 ways.
// ---------------------------------------------------------------------------
__global__ __launch_bounds__(256, 4) void k_pass1(float* __restrict__ ws) {
  __shared__ float sred[4][8];
  const float4* u4 = (const float4*)(ws + OFF_U4);
  const float4* w4 = (const float4*)(ws + OFF_W4);
  float2* rowst = (float2*)(ws + OFF_ROW);
  int tid = threadIdx.x, wid = tid >> 6, lane = tid & 63;
  int g0 = blockIdx.x * 8;
  int b = g0 >> 12;

  float ux[8], uy[8], uz[8], us[8];
#pragma unroll
  for (int r = 0; r < 8; r++) {
    float4 u = u4[g0 + r];
    ux[r] = u.x; uy[r] = u.y; uz[r] = u.z; us[r] = u.w;
  }
  const float4* wb = w4 + b * NN;

  // Loop A: max d2 (no transcendentals)
  float mx[8] = {0.f, 0.f, 0.f, 0.f, 0.f, 0.f, 0.f, 0.f};
  for (int j = wid * 64 + lane; j < NN; j += 256) {
    float4 w = wb[j];
#pragma unroll
    for (int r = 0; r < 8; r++) {
      float dot = ux[r] * w.x + uy[r] * w.y + uz[r] * w.z;
      mx[r] = fmaxf(mx[r], us[r] - dot * dot);
    }
  }
#pragma unroll
  for (int off = 32; off; off >>= 1)
#pragma unroll
    for (int r = 0; r < 8; r++) mx[r] = fmaxf(mx[r], __shfl_xor(mx[r], off));
  if (lane == 0) {
#pragma unroll
    for (int r = 0; r < 8; r++) sred[wid][r] = mx[r];
  }
  __syncthreads();
  float m[8];
#pragma unroll
  for (int r = 0; r < 8; r++)
    m[r] = 50.f * fsqrt(fmaxf(fmaxf(sred[0][r], sred[1][r]), fmaxf(sred[2][r], sred[3][r])));
  __syncthreads();

  // Loop B: sum exp(t - m)
  float s[8] = {0.f, 0.f, 0.f, 0.f, 0.f, 0.f, 0.f, 0.f};
  for (int j = wid * 64 + lane; j < NN; j += 256) {
    float4 w = wb[j];
#pragma unroll
    for (int r = 0; r < 8; r++) {
      float dot = ux[r] * w.x + uy[r] * w.y + uz[r] * w.z;
      float d2 = fmaxf(us[r] - dot * dot, 0.f);
      float t = 50.f * fsqrt(d2);
      s[r] += __expf(t - m[r]);
    }
  }
#pragma unroll
  for (int off = 32; off; off >>= 1)
#pragma unroll
    for (int r = 0; r < 8; r++) s[r] += __shfl_xor(s[r], off);
  if (lane == 0) {
#pragma unroll
    for (int r = 0; r < 8; r++) sred[wid][r] = s[r];
  }
  __syncthreads();
  if (tid < 8) {
    float tot = sred[0][tid] + sred[1][tid] + sred[2][tid] + sred[3][tid];
    rowst[g0 + tid] = make_float2(m[tid], 1.f / tot);
  }
}

// ---------------------------------------------------------------------------
// Pass 2: column softmax denominator over i, subtracting the Cauchy-Schwarz
// bound Mb_j = |tar_j| * max_i|src_i| (>= true max of Aw; exp args <= 0,
// S >= N*exp(-2*Mb) stays fp32-normal; softmax ratio exact for any shift).
// Block = 4 waves on 8 columns.
// ---------------------------------------------------------------------------
__global__ __launch_bounds__(256, 4) void k_pass2(float* __restrict__ ws) {
  __shared__ float sred[4][8];
  const float4* u4 = (const float4*)(ws + OFF_U4);
  const float4* w4 = (const float4*)(ws + OFF_W4);
  const float4* src4 = (const float4*)(ws + OFF_SRC4);
  const float4* tar4 = (const float4*)(ws + OFF_TAR4);
  const float2* rowst = (const float2*)(ws + OFF_ROW);
  float2* colst = (float2*)(ws + OFF_COL);
  int tid = threadIdx.x, wid = tid >> 6, lane = tid & 63;
  int c0 = blockIdx.x * 8;
  int b = c0 >> 12;
  int base = b * NN;
  float maxns = ws[OFF_NMAX + b];

  float wx[8], wy[8], wz[8], tx[8], ty[8], tz[8], Mb[8];
#pragma unroll
  for (int r = 0; r < 8; r++) {
    float4 w = w4[c0 + r];
    float4 tt = tar4[c0 + r];
    wx[r] = w.x; wy[r] = w.y; wz[r] = w.z;
    tx[r] = tt.x; ty[r] = tt.y; tz[r] = tt.z;
    Mb[r] = maxns * fsqrt(tt.x * tt.x + tt.y * tt.y + tt.z * tt.z);
  }

  float S[8] = {0.f, 0.f, 0.f, 0.f, 0.f, 0.f, 0.f, 0.f};
  for (int i = wid * 64 + lane; i < NN; i += 256) {
    float4 u = u4[base + i];
    float4 sv = src4[base + i];
    float2 rs = rowst[base + i];
#pragma unroll
    for (int r = 0; r < 8; r++) {
      float dot = u.x * wx[r] + u.y * wy[r] + u.z * wz[r];
      float d2 = fmaxf(u.w - dot * dot, 0.f);
      float t = 50.f * fsqrt(d2);
      float e = __expf(t - rs.x);
      float wgt = 1.f - e * rs.y;
      float A = sv.x * tx[r] + sv.y * ty[r] + sv.z * tz[r];
      S[r] += __expf(A * wgt - Mb[r]);
    }
  }
#pragma unroll
  for (int off = 32; off; off >>= 1)
#pragma unroll
    for (int r = 0; r < 8; r++) S[r] += __shfl_xor(S[r], off);
  if (lane == 0) {
#pragma unroll
    for (int r = 0; r < 8; r++) sred[wid][r] = S[r];
  }
  __syncthreads();
  if (tid < 8) {
    float tot = sred[0][tid] + sred[1][tid] + sred[2][tid] + sred[3][tid];
    colst[c0 + tid] = make_float2(Mb[tid], 1.f / tot);
  }
}

// ---------------------------------------------------------------------------
// Pass 3: out[b,i,c] = sum_j exp(Aw_ij - Mb_j)/S_j * src[c,j].
// Block = 4 waves on 8 rows, j split 4 ways, LDS merge.
// ---------------------------------------------------------------------------
__global__ __launch_bounds__(256, 4) void k_pass3(const float* __restrict__ ws,
                                                  float* __restrict__ out) {
  __shared__ float sacc[4][24];
  const float4* u4 = (const float4*)(ws + OFF_U4);
  const float4* w4 = (const float4*)(ws + OFF_W4);
  const float4* src4 = (const float4*)(ws + OFF_SRC4);
  const float4* tar4 = (const float4*)(ws + OFF_TAR4);
  const float2* rowst = (const float2*)(ws + OFF_ROW);
  const float2* colst = (const float2*)(ws + OFF_COL);
  int tid = threadIdx.x, wid = tid >> 6, lane = tid & 63;
  int g0 = blockIdx.x * 8;
  int b = g0 >> 12;
  int base = b * NN;

  float ux[8], uy[8], uz[8], us[8], mrow[8], invden[8], sx[8], sy[8], sz[8];
#pragma unroll
  for (int r = 0; r < 8; r++) {
    float4 u = u4[g0 + r];
    float2 rs = rowst[g0 + r];
    float4 sv = src4[g0 + r];
    ux[r] = u.x; uy[r] = u.y; uz[r] = u.z; us[r] = u.w;
    mrow[r] = rs.x; invden[r] = rs.y;
    sx[r] = sv.x; sy[r] = sv.y; sz[r] = sv.z;
  }
  float acc[8][3];
#pragma unroll
  for (int r = 0; r < 8; r++) { acc[r][0] = 0.f; acc[r][1] = 0.f; acc[r][2] = 0.f; }

  for (int j = wid * 64 + lane; j < NN; j += 256) {
    float4 w = w4[base + j];
    float4 tt = tar4[base + j];
    float4 sj = src4[base + j];
    float2 cs = colst[base + j];
#pragma unroll
    for (int r = 0; r < 8; r++) {
      float dot = ux[r] * w.x + uy[r] * w.y + uz[r] * w.z;
      float d2 = fmaxf(us[r] - dot * dot, 0.f);
      float t = 50.f * fsqrt(d2);
      float e = __expf(t - mrow[r]);
      float wgt = 1.f - e * invden[r];
      float A = sx[r] * tt.x + sy[r] * tt.y + sz[r] * tt.z;
      float p = __expf(A * wgt - cs.x) * cs.y;
      acc[r][0] += p * sj.x;
      acc[r][1] += p * sj.y;
      acc[r][2] += p * sj.z;
    }
  }
#pragma unroll
  for (int off = 32; off; off >>= 1)
#pragma unroll
    for (int r = 0; r < 8; r++) {
      acc[r][0] += __shfl_xor(acc[r][0], off);
      acc[r][1] += __shfl_xor(acc[r][1], off);
      acc[r][2] += __shfl_xor(acc[r][2], off);
    }
  if (lane == 0) {
#pragma unroll
    for (int r = 0; r < 8; r++) {
      sacc[wid][r * 3 + 0] = acc[r][0];
      sacc[wid][r * 3 + 1] = acc[r][1];
      sacc[wid][r * 3 + 2] = acc[r][2];
    }
  }
  __syncthreads();
  if (tid < 24) {
    float v = sacc[0][tid] + sacc[1][tid] + sacc[2][tid] + sacc[3][tid];
    out[g0 * 3 + tid] = v;
  }
}

extern "C" void kernel_launch(void* const* d_in, const int* in_sizes, int n_in,
                              void* d_out, int out_size, void* d_ws, size_t ws_size,
                              hipStream_t stream) {
  (void)in_sizes; (void)n_in; (void)out_size; (void)ws_size;
  const float* ftar = (const float*)d_in[0];
  const float* fsrc = (const float*)d_in[1];
  const float* K = (const float*)d_in[2];
  const float* R = (const float*)d_in[3];
  const float* t = (const float*)d_in[4];
  float* ws = (float*)d_ws;
  float* out = (float*)d_out;

  // zero the per-batch norm-max slots (ws is re-poisoned before every call)
  hipMemsetAsync((char*)d_ws + OFF_NMAX * sizeof(float), 0, BB * sizeof(float), stream);

  k_setup<<<dim3((BB * NN + 255) / 256), dim3(256), 0, stream>>>(fsrc, ftar, K, R, t, ws);
  // 8192 rows(/cols) / 8 per block, 4 waves cooperate per block -> 1024 blocks
  k_pass1<<<dim3(1024), dim3(256), 0, stream>>>(ws);
  k_pass2<<<dim3(1024), dim3(256), 0, stream>>>(ws);
  k_pass3<<<dim3(1024), dim3(256), 0, stream>>>(ws, out);
}